// Round 1
// baseline (1030.171 us; speedup 1.0000x reference)
//
#include <hip/hip_runtime.h>
#include <hip/hip_bf16.h>
#include <stdint.h>

#define BB   256
#define DD   64
#define LLEN 50
#define PDIM 10
#define CDIM 8
#define NITEMS 1000000
#define TOPK 20
#define TILE 64

// ---- sortable key: larger key == better (higher score, then lower index) ----
__device__ __forceinline__ unsigned long long pack_key(float s, unsigned n) {
    unsigned sb = __float_as_uint(s);
    sb = (sb & 0x80000000u) ? ~sb : (sb | 0x80000000u);
    return ((unsigned long long)sb << 32) | (unsigned)(~n);
}

// ---- sorted-descending insertion into a 20-entry register array ----
// best[0] largest .. best[19] smallest. Caller guards key > best[19].
__device__ __forceinline__ void insert20(unsigned long long (&best)[TOPK],
                                         unsigned long long key) {
    unsigned long long prev = ~0ull;  // +inf sentinel at j=-1
    #pragma unroll
    for (int j = 0; j < TOPK; ++j) {
        unsigned long long cur = best[j];
        best[j] = (key > cur) ? ((key > prev) ? prev : key) : cur;
        prev = cur;
    }
}

// ================= Phase A: user tower -> u[256][64] (f32, in ws) ============
__global__ __launch_bounds__(64) void user_kernel(
        const int* __restrict__ profile,      // [B,10]
        const int* __restrict__ context,      // [B,50,8]
        const int* __restrict__ item_idx,     // [B,50]
        const float* __restrict__ iv,         // [N,64]
        const float* __restrict__ Wp,         // [10,64]
        const float* __restrict__ Wc,         // [8,64]
        const float* __restrict__ Wu,         // [64,64]
        const float* __restrict__ bu,         // [64]
        float* __restrict__ u_out)            // [B,64]
{
    const int b = blockIdx.x;
    const int d = threadIdx.x;   // 0..63

    // p = profile @ Wp
    float p = 0.f;
    #pragma unroll
    for (int j = 0; j < PDIM; ++j)
        p += (float)profile[b * PDIM + j] * Wp[j * DD + d];

    // c = mean_l(context) @ Wc   (int sums are exact; values<1000, L=50 < 2^24)
    float c = 0.f;
    #pragma unroll
    for (int j = 0; j < CDIM; ++j) {
        int s = 0;
        for (int l = 0; l < LLEN; ++l)
            s += context[(b * LLEN + l) * CDIM + j];
        c += ((float)s * (1.f / (float)LLEN)) * Wc[j * DD + d];
    }

    // i = mean_l items  (gather; coalesced across d)
    float si = 0.f;
    for (int l = 0; l < LLEN; ++l) {
        size_t n = (size_t)item_idx[b * LLEN + l];
        si += iv[n * DD + d];
    }
    si *= (1.f / (float)LLEN);

    __shared__ float sh[DD];
    sh[d] = p + c + si;
    __syncthreads();

    float acc = bu[d];
    #pragma unroll
    for (int dd = 0; dd < DD; ++dd)
        acc = fmaf(sh[dd], Wu[dd * DD + d], acc);

    u_out[b * DD + d] = tanhf(acc);
}

// ============ Phase B: score chunk of items vs all 256 users, local top-20 ===
// thread t == user t. Items staged in LDS tiles; uniform broadcast reads.
__global__ __launch_bounds__(256) void score_kernel(
        const float* __restrict__ iv,          // [N,64]
        const float* __restrict__ u_all,       // [256,64]
        unsigned long long* __restrict__ part, // [B][nblk][20]
        int chunk, int nblk)
{
    __shared__ float lit[TILE][DD];   // 16 KB
    const int t   = threadIdx.x;
    const int blk = blockIdx.x;
    const long base = (long)blk * (long)chunk;

    // user vector -> 64 VGPRs
    float u[DD];
    #pragma unroll
    for (int q = 0; q < 16; ++q) {
        float4 v = reinterpret_cast<const float4*>(u_all + t * DD)[q];
        u[4 * q + 0] = v.x; u[4 * q + 1] = v.y;
        u[4 * q + 2] = v.z; u[4 * q + 3] = v.w;
    }

    unsigned long long best[TOPK];
    #pragma unroll
    for (int k = 0; k < TOPK; ++k) best[k] = 0ull;

    for (long off = 0; off < chunk; off += TILE) {
        __syncthreads();   // previous tile fully consumed
        // cooperative load: 64 items x 64 floats = 1024 float4; 4 per thread
        #pragma unroll
        for (int r = 0; r < 4; ++r) {
            int fi = r * 256 + t;                 // float4 slot 0..1023
            long n = base + off + (fi >> 4);      // 16 float4 per item row
            float4 v = make_float4(0.f, 0.f, 0.f, 0.f);
            if (n < NITEMS)
                v = reinterpret_cast<const float4*>(iv)[(size_t)n * 16 + (fi & 15)];
            reinterpret_cast<float4*>(&lit[0][0])[fi] = v;
        }
        __syncthreads();

        long rem = (long)NITEMS - (base + off);
        int lim = (rem < (long)TILE) ? (int)rem : TILE;
        for (int i = 0; i < lim; ++i) {
            const float4* ivl = reinterpret_cast<const float4*>(&lit[i][0]);
            float acc = 0.f;
            #pragma unroll
            for (int q = 0; q < 16; ++q) {
                float4 w = ivl[q];
                acc = fmaf(u[4 * q + 0], w.x, acc);
                acc = fmaf(u[4 * q + 1], w.y, acc);
                acc = fmaf(u[4 * q + 2], w.z, acc);
                acc = fmaf(u[4 * q + 3], w.w, acc);
            }
            unsigned long long key = pack_key(acc, (unsigned)(base + off + i));
            if (key > best[TOPK - 1]) insert20(best, key);
        }
    }

    // partials laid out [user][blk][20] so phase C reads one contiguous run
    unsigned long long* dst = part + ((size_t)t * nblk + blk) * TOPK;
    #pragma unroll
    for (int k = 0; k < TOPK; ++k) dst[k] = best[k];
}

// ================= Phase C: merge per-user partials -> top-20 indices ========
__global__ __launch_bounds__(256) void merge_kernel(
        const unsigned long long* __restrict__ part, // [B][nblk][20]
        int* __restrict__ out,                       // [B,20]
        int nblk)
{
    const int b = blockIdx.x;
    const int t = threadIdx.x;
    const unsigned long long* src = part + (size_t)b * nblk * TOPK;
    const int total = nblk * TOPK;

    unsigned long long best[TOPK];
    #pragma unroll
    for (int k = 0; k < TOPK; ++k) best[k] = 0ull;

    for (int i = t; i < total; i += 256) {      // coalesced u64 reads
        unsigned long long key = src[i];
        if (key > best[TOPK - 1]) insert20(best, key);
    }

    __shared__ unsigned long long cand[256 * TOPK];  // 40 KB
    __shared__ unsigned long long wmax[4];
    #pragma unroll
    for (int k = 0; k < TOPK; ++k) cand[t * TOPK + k] = best[k];
    __syncthreads();

    int own = 0;  // how many of this thread's sorted list already consumed
    for (int round = 0; round < TOPK; ++round) {
        unsigned long long v = (own < TOPK) ? cand[t * TOPK + own] : 0ull;
        unsigned long long m = v;
        #pragma unroll
        for (int s = 32; s > 0; s >>= 1) {
            unsigned long long o = __shfl_xor(m, s);  // width 64 on CDNA
            m = (o > m) ? o : m;
        }
        if ((t & 63) == 0) wmax[t >> 6] = m;
        __syncthreads();
        unsigned long long g01 = (wmax[0] > wmax[1]) ? wmax[0] : wmax[1];
        unsigned long long g23 = (wmax[2] > wmax[3]) ? wmax[2] : wmax[3];
        unsigned long long g = (g01 > g23) ? g01 : g23;
        if (v == g && v != 0ull) own++;  // keys are globally unique
        if (t == 0) out[b * TOPK + round] = (int)(~(unsigned)(g & 0xFFFFFFFFull));
        __syncthreads();
    }
}

// =============================================================================
extern "C" void kernel_launch(void* const* d_in, const int* in_sizes, int n_in,
                              void* d_out, int out_size, void* d_ws, size_t ws_size,
                              hipStream_t stream) {
    const int*   profile  = (const int*)d_in[0];
    const int*   context  = (const int*)d_in[1];
    const int*   item_idx = (const int*)d_in[2];
    const float* iv       = (const float*)d_in[3];
    const float* Wp       = (const float*)d_in[4];
    const float* Wc       = (const float*)d_in[5];
    const float* Wu       = (const float*)d_in[6];
    const float* bu       = (const float*)d_in[7];

    float* u = (float*)d_ws;                       // 256*64*4 = 64 KB
    const size_t off_part = 65536;
    unsigned long long* part =
        (unsigned long long*)((char*)d_ws + off_part);

    // choose chunk so partials fit in ws: part needs nblk*256*20*8 bytes
    size_t avail = (ws_size > off_part) ? (ws_size - off_part) : 0;
    long maxblk = (long)(avail / ((size_t)BB * TOPK * 8));
    if (maxblk < 1) maxblk = 1;                    // (ws assumed sane)
    int chunk = 1024;                               // -> 977 blocks, ~38 MB ws
    int nblk = (NITEMS + chunk - 1) / chunk;
    if (nblk > maxblk) {
        chunk = (int)(((NITEMS + maxblk - 1) / maxblk + TILE - 1) / TILE) * TILE;
        nblk = (NITEMS + chunk - 1) / chunk;
    }

    user_kernel<<<BB, DD, 0, stream>>>(profile, context, item_idx, iv,
                                       Wp, Wc, Wu, bu, u);
    score_kernel<<<nblk, 256, 0, stream>>>(iv, u, part, chunk, nblk);
    merge_kernel<<<BB, 256, 0, stream>>>(part, (int*)d_out, nblk);
}